// Round 1
// baseline (221.124 us; speedup 1.0000x reference)
//
#include <hip/hip_runtime.h>
#include <hip/hip_bf16.h>

// ---------- types ----------
typedef __attribute__((ext_vector_type(8))) short bf16x8;
typedef __attribute__((ext_vector_type(4))) float f32x4;
typedef __attribute__((ext_vector_type(16))) float f32x16;
typedef __attribute__((ext_vector_type(4))) unsigned u32x4;

#define DEVINL static __device__ __forceinline__
#define GLOBAL_AS __attribute__((address_space(1)))
#define LDS_AS __attribute__((address_space(3)))

DEVINL short f2b(float f) {
  __hip_bfloat16 h = __float2bfloat16(f);
  return __builtin_bit_cast(short, h);
}
DEVINL float b2f(short s) {
  return __bfloat162float(__builtin_bit_cast(__hip_bfloat16, s));
}
DEVINL unsigned pack2(float a, float b) {
  return (unsigned)(unsigned short)f2b(a) | ((unsigned)(unsigned short)f2b(b) << 16);
}
DEVINL void load_lds16(const void* g, void* l) {
  __builtin_amdgcn_global_load_lds((const GLOBAL_AS void*)g, (LDS_AS void*)l, 16, 0, 0);
}
DEVINL void barrier_raw() {
  __builtin_amdgcn_sched_barrier(0);
  __builtin_amdgcn_s_barrier();
  __builtin_amdgcn_sched_barrier(0);
}
DEVINL f32x16 mfma32(bf16x8 a, bf16x8 b, f32x16 c) {
  return __builtin_amdgcn_mfma_f32_32x32x16_bf16(a, b, c, 0, 0, 0);
}
DEVINL f32x16 zero16() {
  f32x16 z;
#pragma unroll
  for (int i = 0; i < 16; ++i) z[i] = 0.f;
  return z;
}

// ---------- fused fp32 -> bf16 conversion (x, Wq, Wk, Wv, Wo in one launch) ----------
// unit = 8 elems. Segments: x 1048576 | Wq 524288 | Wk 32768 | Wv 32768 | Wo 524288.
__global__ __launch_bounds__(256) void cvt_all_kernel(const float* __restrict__ x,
                                                      const float* __restrict__ wq,
                                                      const float* __restrict__ wk,
                                                      const float* __restrict__ wv,
                                                      const float* __restrict__ wo,
                                                      short* __restrict__ xb,
                                                      short* __restrict__ wcat,
                                                      short* __restrict__ wob) {
  int i = blockIdx.x * blockDim.x + threadIdx.x;
  if (i >= 2162688) return;
  const float* src;
  short* dst;
  if (i < 1048576) {
    src = x + (size_t)i * 8;
    dst = xb + (size_t)i * 8;
  } else if (i < 1572864) {
    int j = i - 1048576;
    src = wq + (size_t)j * 8;
    dst = wcat + (size_t)j * 8;
  } else if (i < 1605632) {
    int j = i - 1572864;
    src = wk + (size_t)j * 8;
    dst = wcat + 4194304 + (size_t)j * 8;
  } else if (i < 1638400) {
    int j = i - 1605632;
    src = wv + (size_t)j * 8;
    dst = wcat + 4456448 + (size_t)j * 8;
  } else {
    int j = i - 1638400;
    src = wo + (size_t)j * 8;
    dst = wob + (size_t)j * 8;
  }
  const float4* p = reinterpret_cast<const float4*>(src);
  float4 a = p[0], b = p[1];
  bf16x8 v;
  v[0] = f2b(a.x); v[1] = f2b(a.y); v[2] = f2b(a.z); v[3] = f2b(a.w);
  v[4] = f2b(b.x); v[5] = f2b(b.y); v[6] = f2b(b.z); v[7] = f2b(b.w);
  *reinterpret_cast<bf16x8*>(dst) = v;
}

// ---------- NT GEMM: C[m][n] = sum_k A[m][k]*B[n][k], A [M][K], B [N][K] bf16 ----------
// 1D grid with XCD-bijective swizzle (nwg % 8 == 0 required; 576 and 512 both ok).
template <int BF16OUT>
__global__ __launch_bounds__(256) void gemm_nt(const short* __restrict__ A,
                                               const short* __restrict__ B,
                                               void* __restrict__ Cv, int M, int N, int K) {
  __shared__ short As[128 * 64];
  __shared__ short Bs[128 * 64];
  const int tid = threadIdx.x;
  const int lane = tid & 63;
  const int wid = tid >> 6;
  const int lr = lane & 15, lg = lane >> 4;
  // XCD swizzle: each XCD gets a contiguous chunk of the swizzled id space
  const int nwg = gridDim.x, cpx = nwg >> 3;
  const int lid = blockIdx.x;
  const int swz = (lid & 7) * cpx + (lid >> 3);
  const int nbn = N >> 7;
  const int bn = swz % nbn, bm = swz / nbn;
  const int wr = wid >> 1, wc = wid & 1;

  f32x4 acc[4][4];
#pragma unroll
  for (int i = 0; i < 4; ++i)
#pragma unroll
    for (int j = 0; j < 4; ++j) acc[i][j] = f32x4{0.f, 0.f, 0.f, 0.f};

  const short* Ag[4];
  const short* Bg[4];
#pragma unroll
  for (int j = 0; j < 4; ++j) {
    int o = j * 4096 + tid * 16;          // linear LDS byte offset
    int row = o >> 7;                     // 128-B rows
    int src = o ^ ((row & 7) << 4);       // pre-swizzled source byte offset in tile
    int col = (src & 127) >> 1;           // bf16 col within BK
    Ag[j] = A + (size_t)(bm * 128 + row) * K + col;
    Bg[j] = B + (size_t)(bn * 128 + row) * K + col;
  }
  char* Asb = (char*)As;
  char* Bsb = (char*)Bs;
  const int lds_w = wid * 1024;

  for (int kt = 0; kt < K; kt += 64) {
    __syncthreads();
#pragma unroll
    for (int j = 0; j < 4; ++j) load_lds16(Ag[j] + kt, Asb + j * 4096 + lds_w);
#pragma unroll
    for (int j = 0; j < 4; ++j) load_lds16(Bg[j] + kt, Bsb + j * 4096 + lds_w);
    __syncthreads();

#pragma unroll
    for (int kc = 0; kc < 2; ++kc) {
      bf16x8 af[4], bfr[4];
#pragma unroll
      for (int mf = 0; mf < 4; ++mf) {
        int row = wr * 64 + mf * 16 + lr;
        int a_ = (row * 128 + kc * 64 + lg * 16) ^ ((row & 7) << 4);
        af[mf] = *(const bf16x8*)(Asb + a_);
      }
#pragma unroll
      for (int nf = 0; nf < 4; ++nf) {
        int row = wc * 64 + nf * 16 + lr;
        int a_ = (row * 128 + kc * 64 + lg * 16) ^ ((row & 7) << 4);
        bfr[nf] = *(const bf16x8*)(Bsb + a_);
      }
#pragma unroll
      for (int mf = 0; mf < 4; ++mf)
#pragma unroll
        for (int nf = 0; nf < 4; ++nf)
          acc[mf][nf] =
              __builtin_amdgcn_mfma_f32_16x16x32_bf16(af[mf], bfr[nf], acc[mf][nf], 0, 0, 0);
    }
  }

#pragma unroll
  for (int mf = 0; mf < 4; ++mf)
#pragma unroll
    for (int nf = 0; nf < 4; ++nf)
#pragma unroll
      for (int j = 0; j < 4; ++j) {
        int row = bm * 128 + wr * 64 + mf * 16 + lg * 4 + j;
        int col = bn * 128 + wc * 64 + nf * 16 + lr;
        if constexpr (BF16OUT)
          ((short*)Cv)[(size_t)row * N + col] = f2b(acc[mf][nf][j]);
        else
          ((float*)Cv)[(size_t)row * N + col] = acc[mf][nf][j];
      }
}

// ---------- RoPE: qkv [B*T][2304] -> qh [B][H][T][128] (q pre-scaled), kh [B][T][128] ----------
// Q is pre-scaled by (1/sqrt(T)) * log2(e) so attention can use exp2 directly.
#define QSC 0.031879358f
__global__ __launch_bounds__(256) void rope_kernel(const short* __restrict__ qkv,
                                                   const float* __restrict__ cosb,
                                                   const float* __restrict__ sinb,
                                                   short* __restrict__ qh,
                                                   short* __restrict__ kh) {
  const int bt = blockIdx.x;  // b*2048 + t
  const int b = bt >> 11, t = bt & 2047;
  const int tid = threadIdx.x;
  {
    int h = tid >> 4, d0 = (tid & 15) * 8;
    const short* base = qkv + (size_t)bt * 2304 + h * 128;
    bf16x8 qa = *(const bf16x8*)(base + d0);
    int dp = d0 < 64 ? d0 + 64 : d0 - 64;
    bf16x8 qp = *(const bf16x8*)(base + dp);
    const float* cp = cosb + (size_t)bt * 128 + d0;
    const float* sp = sinb + (size_t)bt * 128 + d0;
    float sgn = d0 < 64 ? -1.f : 1.f;
    bf16x8 r;
#pragma unroll
    for (int e = 0; e < 8; ++e)
      r[e] = f2b((b2f(qa[e]) * cp[e] + sgn * b2f(qp[e]) * sp[e]) * QSC);
    *(bf16x8*)(qh + (((size_t)(b * 16 + h) * 2048 + t) * 128 + d0)) = r;
  }
  if (tid < 16) {
    int d0 = tid * 8;
    const short* base = qkv + (size_t)bt * 2304 + 2048;
    bf16x8 ka = *(const bf16x8*)(base + d0);
    int dp = d0 < 64 ? d0 + 64 : d0 - 64;
    bf16x8 kp = *(const bf16x8*)(base + dp);
    const float* cp = cosb + (size_t)bt * 128 + d0;
    const float* sp = sinb + (size_t)bt * 128 + d0;
    float sgn = d0 < 64 ? -1.f : 1.f;
    bf16x8 r;
#pragma unroll
    for (int e = 0; e < 8; ++e)
      r[e] = f2b(b2f(ka[e]) * cp[e] + sgn * b2f(kp[e]) * sp[e]);
    *(bf16x8*)(kh + ((size_t)bt * 128 + d0)) = r;
  }
}

// ---------- V transpose: qkv v-cols -> vt [B][128][T] ----------
__global__ __launch_bounds__(256) void vtrans_kernel(const short* __restrict__ qkv,
                                                     short* __restrict__ vt) {
  __shared__ short tile[64][33];
  const int tid = threadIdx.x;
  const int t0 = blockIdx.x * 64, d0 = blockIdx.y * 32, b = blockIdx.z;
  {
    int dl = tid & 31, tl0 = tid >> 5;
#pragma unroll
    for (int r = 0; r < 8; ++r) {
      int tl = tl0 + r * 8;
      tile[tl][dl] = qkv[(size_t)(b * 2048 + t0 + tl) * 2304 + 2176 + d0 + dl];
    }
  }
  __syncthreads();
  {
    int dl = tid >> 3, s0 = (tid & 7) * 8;
    bf16x8 v;
#pragma unroll
    for (int e = 0; e < 8; ++e) v[e] = tile[s0 + e][dl];
    *(bf16x8*)(vt + (size_t)(b * 128 + d0 + dl) * 2048 + t0 + s0) = v;
  }
}

// ---------- causal MQA flash attention v10: 4-wave kv-split ----------
// grid (16, H, B), 256 threads = 4 waves. Waves (0,1): q-halves 0/1 x kv rows [0,32)
// of each 64-row K/V tile; waves (2,3): same q-halves x kv rows [32,64). Static-max
// softmax (Q pre-scaled, P = exp2(S)) makes kv-partials purely ADDITIVE: partial O^T
// and partial row-sums combine by addition at phase end (via LDS, reusing K bufs).
// This doubles waves/SIMD (1 -> 2) at unchanged LDS (64 KiB) and unchanged total
// MFMA/staging work: the occupancy fix for the 10.7% -> ~21% latency bottleneck.
// Per iteration: vmcnt(0) -> barrier -> STAGE(next -> p^1) -> compute(p).
__global__ __launch_bounds__(256) void attn_kernel(const short* __restrict__ qh,
                                                   const short* __restrict__ kh,
                                                   const short* __restrict__ vt,
                                                   short* __restrict__ ao) {
  __shared__ short Ks[2][64 * 128];
  __shared__ short Vts[2][128 * 64];
  const int tid = threadIdx.x, lane = tid & 63, wid = tid >> 6;
  const int c = lane & 31, hi = lane >> 5;
  const int wq = wid & 1;   // q-half (32 rows)
  const int wp = wid >> 1;  // kv-half (32 rows of the 64-row tile)
  const int pi = blockIdx.x;  // 0..15
  const int h = blockIdx.y, b = blockIdx.z;

  // staging source (pre-swizzled global addresses; LDS dest stays linear)
  const int o = tid * 16;                      // byte offset within a 4KB round
  const int ksrc = o ^ (((o >> 8) & 7) << 4);  // K tile: 256-B rows
  const int vsrc = o ^ (((o >> 7) & 7) << 4);  // Vt tile: 128-B rows
  const char* kg = (const char*)kh + (size_t)b * 524288 + ksrc;
  const char* vg = (const char*)vt + (size_t)b * 524288 + ((o >> 7) * 4096 + (vsrc & 127));
  const int ldsw = wid * 1024;

  auto STAGE = [&](int bufp, int st) {
    const int s0 = st * 64;
    char* kd = (char*)Ks[bufp] + ldsw;
    char* vd = (char*)Vts[bufp] + ldsw;
    const char* kgs = kg + s0 * 256;
    const char* vgs = vg + s0 * 2;
#pragma unroll
    for (int j = 0; j < 4; ++j) load_lds16(kgs + j * 4096, kd + j * 4096);
#pragma unroll
    for (int j = 0; j < 4; ++j) load_lds16(vgs + j * 131072, vd + j * 4096);
  };

#pragma unroll 1
  for (int ph = 0; ph < 2; ++ph) {
    const int qt = ph ? (31 - pi) : pi;
    const int q0 = qt * 64 + wq * 32;
    const int qv = q0 + c;

    bf16x8 qf[8];
    const short* qbase = qh + ((size_t)(b * 16 + h) * 2048 + qv) * 128;
#pragma unroll
    for (int ki = 0; ki < 8; ++ki) qf[ki] = *(const bf16x8*)(qbase + ki * 16 + hi * 8);

    f32x16 OT[4];
#pragma unroll
    for (int d = 0; d < 4; ++d) OT[d] = zero16();
    float lsum = 0.f;

    const int n = qt + 1;
    if (ph) __syncthreads();  // all waves done with LDS (combine reads) before re-staging
    STAGE(0, 0);
    int p = 0;
#pragma unroll 1
    for (int st = 0; st < n; ++st) {
      const int s0 = st * 64 + wp * 32;  // this wave's kv base
      asm volatile("s_waitcnt vmcnt(0)" ::: "memory");
      barrier_raw();
      if (st + 1 < n) STAGE(p ^ 1, st + 1);

      const char* Ksb = (const char*)Ks[p] + wp * 8192;
      const char* Vtb = (const char*)Vts[p];

      // S[kv][q] = K Q^T  (one 32-kv block per wave)
      f32x16 S0 = zero16();
      __builtin_amdgcn_s_setprio(1);
#pragma unroll
      for (int ki = 0; ki < 8; ++ki) {
        int a0 = (c * 256 + ki * 32 + hi * 16) ^ ((c & 7) << 4);
        bf16x8 k0 = *(const bf16x8*)(Ksb + a0);
        S0 = mfma32(k0, qf[ki], S0);
      }
      __builtin_amdgcn_s_setprio(0);

      // causal mask (only near-diagonal tiles)
      if (s0 + 31 > q0) {
#pragma unroll
        for (int r = 0; r < 16; ++r) {
          int kv0 = s0 + (r & 3) + 8 * (r >> 2) + hi * 4;
          S0[r] = (kv0 > qv) ? -1e30f : S0[r];
        }
      }

      // P = exp2(S)  (static max = 0; masked entries underflow to 0), 4-acc row-sum
      float ps0 = 0.f, ps1 = 0.f, ps2 = 0.f, ps3 = 0.f;
#pragma unroll
      for (int r = 0; r < 16; r += 4) {
        S0[r] = exp2f(S0[r]);          ps0 += S0[r];
        S0[r + 1] = exp2f(S0[r + 1]);  ps1 += S0[r + 1];
        S0[r + 2] = exp2f(S0[r + 2]);  ps2 += S0[r + 2];
        S0[r + 3] = exp2f(S0[r + 3]);  ps3 += S0[r + 3];
      }
      float psum = (ps0 + ps1) + (ps2 + ps3);
      psum += __shfl_xor(psum, 32);
      lsum += psum;

      // pack P to bf16 + cross-half redistribution (proven select table)
      unsigned D[8], sD[8];
#pragma unroll
      for (int i = 0; i < 8; ++i) D[i] = pack2(S0[2 * i], S0[2 * i + 1]);
#pragma unroll
      for (int i = 0; i < 8; ++i) sD[i] = (unsigned)__shfl_xor((int)D[i], 32);
      bf16x8 pf[2];
#pragma unroll
      for (int ks = 0; ks < 2; ++ks) {
        int bi = ks * 4;
        u32x4 w;
        w[0] = hi ? sD[bi + 2] : D[bi + 0];
        w[1] = hi ? sD[bi + 3] : D[bi + 1];
        w[2] = hi ? D[bi + 2] : sD[bi + 0];
        w[3] = hi ? D[bi + 3] : sD[bi + 1];
        pf[ks] = __builtin_bit_cast(bf16x8, w);
      }

      // O^T += V^T P  (this wave's 32-kv slice of the Vt tile)
      __builtin_amdgcn_s_setprio(1);
#pragma unroll
      for (int dblk = 0; dblk < 4; ++dblk) {
        int row = dblk * 32 + c;
        int sw = (row & 7) << 4;
#pragma unroll
        for (int ks = 0; ks < 2; ++ks) {
          int a_v = (row * 128 + wp * 64 + ks * 32 + hi * 16) ^ sw;
          bf16x8 vf = *(const bf16x8*)(Vtb + a_v);
          OT[dblk] = mfma32(vf, pf[ks], OT[dblk]);
        }
      }
      __builtin_amdgcn_s_setprio(0);

      p ^= 1;
    }

    // ---- cross-pair combine: wp==1 publishes partials in LDS; wp==0 reduces ----
    __syncthreads();  // all waves done reading K/V bufs; all staging drained
    float* ob = (float*)(Ks[0]) + wq * 4096;   // 16 KiB per q-half (fills Ks[0..1])
    float* lb = (float*)(Vts[0]) + wq * 32;    // 32 floats per q-half
    if (wp == 1) {
#pragma unroll
      for (int dblk = 0; dblk < 4; ++dblk)
#pragma unroll
        for (int rq = 0; rq < 4; ++rq) {
          int off = (lane * 256 + (dblk * 4 + rq) * 16) ^ ((lane & 7) << 4);
          f32x4 piece;
          piece[0] = OT[dblk][4 * rq];
          piece[1] = OT[dblk][4 * rq + 1];
          piece[2] = OT[dblk][4 * rq + 2];
          piece[3] = OT[dblk][4 * rq + 3];
          *(f32x4*)((char*)ob + off) = piece;
        }
      if (hi == 0) lb[c] = lsum;
    }
    __syncthreads();
    if (wp == 0) {
#pragma unroll
      for (int dblk = 0; dblk < 4; ++dblk)
#pragma unroll
        for (int rq = 0; rq < 4; ++rq) {
          int off = (lane * 256 + (dblk * 4 + rq) * 16) ^ ((lane & 7) << 4);
          f32x4 piece = *(const f32x4*)((const char*)ob + off);
          OT[dblk][4 * rq] += piece[0];
          OT[dblk][4 * rq + 1] += piece[1];
          OT[dblk][4 * rq + 2] += piece[2];
          OT[dblk][4 * rq + 3] += piece[3];
        }
      float inv = 1.f / (lsum + lb[c]);

      // epilogue: O^T / lsum -> ao[b][q][h][d], paired-d dword stores
      short* aob = ao + ((size_t)(b * 2048 + qv) * 2048 + h * 128);
#pragma unroll
      for (int dblk = 0; dblk < 4; ++dblk) {
#pragma unroll
        for (int rp = 0; rp < 8; ++rp) {
          int r = rp * 2;
          int dd = dblk * 32 + (r & 3) + 8 * (r >> 2) + hi * 4;
          unsigned w = pack2(OT[dblk][r] * inv, OT[dblk][r + 1] * inv);
          *(unsigned*)(aob + dd) = w;
        }
      }
    }
  }
}

// ---------- launch ----------
extern "C" void kernel_launch(void* const* d_in, const int* in_sizes, int n_in,
                              void* d_out, int out_size, void* d_ws, size_t ws_size,
                              hipStream_t stream) {
  const float* x = (const float*)d_in[0];
  const float* cosb = (const float*)d_in[1];
  const float* sinb = (const float*)d_in[2];
  const float* Wq = (const float*)d_in[3];
  const float* Wk = (const float*)d_in[4];
  const float* Wv = (const float*)d_in[5];
  const float* Wo = (const float*)d_in[6];

  char* ws = (char*)d_ws;
  short* xb = (short*)(ws);                    // 16.78 MB  (aliased as ao later)
  short* wcat = (short*)(ws + 16777216);       // 9.44 MB
  short* wob = (short*)(ws + 26214400);        // 8.39 MB
  short* qkv = (short*)(ws + 34603008);        // 18.87 MB
  short* qh = (short*)(ws + 53477376);         // 16.78 MB
  short* kh = (short*)(ws + 70254592);         // 1.05 MB
  short* vt = (short*)(ws + 71303168);         // 1.05 MB
  short* ao = xb;                              // xb dead after gemm1

  cvt_all_kernel<<<8448, 256, 0, stream>>>(x, Wq, Wk, Wv, Wo, xb, wcat, wob);

  gemm_nt<1><<<576, 256, 0, stream>>>(xb, wcat, qkv, 4096, 2304, 2048);
  rope_kernel<<<4096, 256, 0, stream>>>(qkv, cosb, sinb, qh, kh);
  vtrans_kernel<<<dim3(32, 4, 2), 256, 0, stream>>>(qkv, vt);
  attn_kernel<<<dim3(16, 16, 2), 256, 0, stream>>>(qh, kh, vt, ao);
  gemm_nt<0><<<512, 256, 0, stream>>>(ao, wob, d_out, 4096, 2048, 2048);
}

// Round 2
// 207.570 us; speedup vs baseline: 1.0653x; 1.0653x over previous
//
#include <hip/hip_runtime.h>
#include <hip/hip_bf16.h>

// ---------- types ----------
typedef __attribute__((ext_vector_type(8))) short bf16x8;
typedef __attribute__((ext_vector_type(4))) float f32x4;
typedef __attribute__((ext_vector_type(16))) float f32x16;
typedef __attribute__((ext_vector_type(4))) unsigned u32x4;

#define DEVINL static __device__ __forceinline__
#define GLOBAL_AS __attribute__((address_space(1)))
#define LDS_AS __attribute__((address_space(3)))

DEVINL short f2b(float f) {
  __hip_bfloat16 h = __float2bfloat16(f);
  return __builtin_bit_cast(short, h);
}
DEVINL float b2f(short s) {
  return __bfloat162float(__builtin_bit_cast(__hip_bfloat16, s));
}
DEVINL unsigned pack2(float a, float b) {
  return (unsigned)(unsigned short)f2b(a) | ((unsigned)(unsigned short)f2b(b) << 16);
}
DEVINL void load_lds16(const void* g, void* l) {
  __builtin_amdgcn_global_load_lds((const GLOBAL_AS void*)g, (LDS_AS void*)l, 16, 0, 0);
}
DEVINL void barrier_raw() {
  __builtin_amdgcn_sched_barrier(0);
  __builtin_amdgcn_s_barrier();
  __builtin_amdgcn_sched_barrier(0);
}
DEVINL f32x16 mfma32(bf16x8 a, bf16x8 b, f32x16 c) {
  return __builtin_amdgcn_mfma_f32_32x32x16_bf16(a, b, c, 0, 0, 0);
}
DEVINL f32x16 zero16() {
  f32x16 z;
#pragma unroll
  for (int i = 0; i < 16; ++i) z[i] = 0.f;
  return z;
}

// ---------- fused fp32 -> bf16 conversion (x, Wq, Wk, Wv, Wo in one launch) ----------
// unit = 8 elems. Segments: x 1048576 | Wq 524288 | Wk 32768 | Wv 32768 | Wo 524288.
__global__ __launch_bounds__(256) void cvt_all_kernel(const float* __restrict__ x,
                                                      const float* __restrict__ wq,
                                                      const float* __restrict__ wk,
                                                      const float* __restrict__ wv,
                                                      const float* __restrict__ wo,
                                                      short* __restrict__ xb,
                                                      short* __restrict__ wcat,
                                                      short* __restrict__ wob) {
  int i = blockIdx.x * blockDim.x + threadIdx.x;
  if (i >= 2162688) return;
  const float* src;
  short* dst;
  if (i < 1048576) {
    src = x + (size_t)i * 8;
    dst = xb + (size_t)i * 8;
  } else if (i < 1572864) {
    int j = i - 1048576;
    src = wq + (size_t)j * 8;
    dst = wcat + (size_t)j * 8;
  } else if (i < 1605632) {
    int j = i - 1572864;
    src = wk + (size_t)j * 8;
    dst = wcat + 4194304 + (size_t)j * 8;
  } else if (i < 1638400) {
    int j = i - 1605632;
    src = wv + (size_t)j * 8;
    dst = wcat + 4456448 + (size_t)j * 8;
  } else {
    int j = i - 1638400;
    src = wo + (size_t)j * 8;
    dst = wob + (size_t)j * 8;
  }
  const float4* p = reinterpret_cast<const float4*>(src);
  float4 a = p[0], b = p[1];
  bf16x8 v;
  v[0] = f2b(a.x); v[1] = f2b(a.y); v[2] = f2b(a.z); v[3] = f2b(a.w);
  v[4] = f2b(b.x); v[5] = f2b(b.y); v[6] = f2b(b.z); v[7] = f2b(b.w);
  *reinterpret_cast<bf16x8*>(dst) = v;
}

// ---------- NT GEMM: C[m][n] = sum_k A[m][k]*B[n][k], A [M][K], B [N][K] bf16 ----------
// 1D grid with XCD-bijective swizzle (nwg % 8 == 0 required; 576 and 512 both ok).
template <int BF16OUT>
__global__ __launch_bounds__(256) void gemm_nt(const short* __restrict__ A,
                                               const short* __restrict__ B,
                                               void* __restrict__ Cv, int M, int N, int K) {
  __shared__ short As[128 * 64];
  __shared__ short Bs[128 * 64];
  const int tid = threadIdx.x;
  const int lane = tid & 63;
  const int wid = tid >> 6;
  const int lr = lane & 15, lg = lane >> 4;
  // XCD swizzle: each XCD gets a contiguous chunk of the swizzled id space
  const int nwg = gridDim.x, cpx = nwg >> 3;
  const int lid = blockIdx.x;
  const int swz = (lid & 7) * cpx + (lid >> 3);
  const int nbn = N >> 7;
  const int bn = swz % nbn, bm = swz / nbn;
  const int wr = wid >> 1, wc = wid & 1;

  f32x4 acc[4][4];
#pragma unroll
  for (int i = 0; i < 4; ++i)
#pragma unroll
    for (int j = 0; j < 4; ++j) acc[i][j] = f32x4{0.f, 0.f, 0.f, 0.f};

  const short* Ag[4];
  const short* Bg[4];
#pragma unroll
  for (int j = 0; j < 4; ++j) {
    int o = j * 4096 + tid * 16;          // linear LDS byte offset
    int row = o >> 7;                     // 128-B rows
    int src = o ^ ((row & 7) << 4);       // pre-swizzled source byte offset in tile
    int col = (src & 127) >> 1;           // bf16 col within BK
    Ag[j] = A + (size_t)(bm * 128 + row) * K + col;
    Bg[j] = B + (size_t)(bn * 128 + row) * K + col;
  }
  char* Asb = (char*)As;
  char* Bsb = (char*)Bs;
  const int lds_w = wid * 1024;

  for (int kt = 0; kt < K; kt += 64) {
    __syncthreads();
#pragma unroll
    for (int j = 0; j < 4; ++j) load_lds16(Ag[j] + kt, Asb + j * 4096 + lds_w);
#pragma unroll
    for (int j = 0; j < 4; ++j) load_lds16(Bg[j] + kt, Bsb + j * 4096 + lds_w);
    __syncthreads();

#pragma unroll
    for (int kc = 0; kc < 2; ++kc) {
      bf16x8 af[4], bfr[4];
#pragma unroll
      for (int mf = 0; mf < 4; ++mf) {
        int row = wr * 64 + mf * 16 + lr;
        int a_ = (row * 128 + kc * 64 + lg * 16) ^ ((row & 7) << 4);
        af[mf] = *(const bf16x8*)(Asb + a_);
      }
#pragma unroll
      for (int nf = 0; nf < 4; ++nf) {
        int row = wc * 64 + nf * 16 + lr;
        int a_ = (row * 128 + kc * 64 + lg * 16) ^ ((row & 7) << 4);
        bfr[nf] = *(const bf16x8*)(Bsb + a_);
      }
#pragma unroll
      for (int mf = 0; mf < 4; ++mf)
#pragma unroll
        for (int nf = 0; nf < 4; ++nf)
          acc[mf][nf] =
              __builtin_amdgcn_mfma_f32_16x16x32_bf16(af[mf], bfr[nf], acc[mf][nf], 0, 0, 0);
    }
  }

#pragma unroll
  for (int mf = 0; mf < 4; ++mf)
#pragma unroll
    for (int nf = 0; nf < 4; ++nf)
#pragma unroll
      for (int j = 0; j < 4; ++j) {
        int row = bm * 128 + wr * 64 + mf * 16 + lg * 4 + j;
        int col = bn * 128 + wc * 64 + nf * 16 + lr;
        if constexpr (BF16OUT)
          ((short*)Cv)[(size_t)row * N + col] = f2b(acc[mf][nf][j]);
        else
          ((float*)Cv)[(size_t)row * N + col] = acc[mf][nf][j];
      }
}

// ---------- RoPE: qkv [B*T][2304] -> qh [B][H][T][128] (q pre-scaled), kh [B][T][128] ----------
// Q is pre-scaled by (1/sqrt(T)) * log2(e) so attention can use exp2 directly.
#define QSC 0.031879358f
__global__ __launch_bounds__(256) void rope_kernel(const short* __restrict__ qkv,
                                                   const float* __restrict__ cosb,
                                                   const float* __restrict__ sinb,
                                                   short* __restrict__ qh,
                                                   short* __restrict__ kh) {
  const int bt = blockIdx.x;  // b*2048 + t
  const int b = bt >> 11, t = bt & 2047;
  const int tid = threadIdx.x;
  {
    int h = tid >> 4, d0 = (tid & 15) * 8;
    const short* base = qkv + (size_t)bt * 2304 + h * 128;
    bf16x8 qa = *(const bf16x8*)(base + d0);
    int dp = d0 < 64 ? d0 + 64 : d0 - 64;
    bf16x8 qp = *(const bf16x8*)(base + dp);
    const float* cp = cosb + (size_t)bt * 128 + d0;
    const float* sp = sinb + (size_t)bt * 128 + d0;
    float sgn = d0 < 64 ? -1.f : 1.f;
    bf16x8 r;
#pragma unroll
    for (int e = 0; e < 8; ++e)
      r[e] = f2b((b2f(qa[e]) * cp[e] + sgn * b2f(qp[e]) * sp[e]) * QSC);
    *(bf16x8*)(qh + (((size_t)(b * 16 + h) * 2048 + t) * 128 + d0)) = r;
  }
  if (tid < 16) {
    int d0 = tid * 8;
    const short* base = qkv + (size_t)bt * 2304 + 2048;
    bf16x8 ka = *(const bf16x8*)(base + d0);
    int dp = d0 < 64 ? d0 + 64 : d0 - 64;
    bf16x8 kp = *(const bf16x8*)(base + dp);
    const float* cp = cosb + (size_t)bt * 128 + d0;
    const float* sp = sinb + (size_t)bt * 128 + d0;
    float sgn = d0 < 64 ? -1.f : 1.f;
    bf16x8 r;
#pragma unroll
    for (int e = 0; e < 8; ++e)
      r[e] = f2b(b2f(ka[e]) * cp[e] + sgn * b2f(kp[e]) * sp[e]);
    *(bf16x8*)(kh + ((size_t)bt * 128 + d0)) = r;
  }
}

// ---------- V transpose: qkv v-cols -> vt [B][128][T] ----------
__global__ __launch_bounds__(256) void vtrans_kernel(const short* __restrict__ qkv,
                                                     short* __restrict__ vt) {
  __shared__ short tile[64][33];
  const int tid = threadIdx.x;
  const int t0 = blockIdx.x * 64, d0 = blockIdx.y * 32, b = blockIdx.z;
  {
    int dl = tid & 31, tl0 = tid >> 5;
#pragma unroll
    for (int r = 0; r < 8; ++r) {
      int tl = tl0 + r * 8;
      tile[tl][dl] = qkv[(size_t)(b * 2048 + t0 + tl) * 2304 + 2176 + d0 + dl];
    }
  }
  __syncthreads();
  {
    int dl = tid >> 3, s0 = (tid & 7) * 8;
    bf16x8 v;
#pragma unroll
    for (int e = 0; e < 8; ++e) v[e] = tile[s0 + e][dl];
    *(bf16x8*)(vt + (size_t)(b * 128 + d0 + dl) * 2048 + t0 + s0) = v;
  }
}

// ---------- causal MQA flash attention v11: 128-q blocks + triple-buffer counted vmcnt ----------
// grid (8, H, B), 256 threads = 4 waves, each wave one 32-q strip of a 128-row q-supertile
// (per-wave math identical to proven v9: full 64-kv step, S0+S1, 16+16 MFMAs). Block pi
// does q-supertiles pi and 15-pi (balanced 36 steps). vs v9: per-CU staging per step
// HALVES (1 block/CU x 32KB instead of 2 x 32KB) and prefetch is depth-2 via TRIPLE
// buffered K/V (96 KiB LDS) with counted vmcnt(8) — loads get ~2 full steps to land and
// the queue never drains in the main loop (T4). Fully-masked waves skip compute on
// diagonal steps. Static-max softmax (Q pre-scaled, P = exp2(S)) as before.
__global__ __launch_bounds__(256) void attn_kernel(const short* __restrict__ qh,
                                                   const short* __restrict__ kh,
                                                   const short* __restrict__ vt,
                                                   short* __restrict__ ao) {
  __shared__ short Ks[3][64 * 128];
  __shared__ short Vts[3][128 * 64];
  const int tid = threadIdx.x, lane = tid & 63, wid = tid >> 6;
  const int c = lane & 31, hi = lane >> 5;
  const int pi = blockIdx.x;  // 0..7
  const int h = blockIdx.y, b = blockIdx.z;

  // staging source (pre-swizzled global addresses; LDS dest stays linear)
  const int o = tid * 16;                      // byte offset within a 4KB round
  const int ksrc = o ^ (((o >> 8) & 7) << 4);  // K tile: 256-B rows
  const int vsrc = o ^ (((o >> 7) & 7) << 4);  // Vt tile: 128-B rows
  const char* kg = (const char*)kh + (size_t)b * 524288 + ksrc;
  const char* vg = (const char*)vt + (size_t)b * 524288 + ((o >> 7) * 4096 + (vsrc & 127));
  const int ldsw = wid * 1024;

  auto STAGE = [&](int bufp, int st) {
    const int s0 = st * 64;
    char* kd = (char*)Ks[bufp] + ldsw;
    char* vd = (char*)Vts[bufp] + ldsw;
    const char* kgs = kg + s0 * 256;
    const char* vgs = vg + s0 * 2;
#pragma unroll
    for (int j = 0; j < 4; ++j) load_lds16(kgs + j * 4096, kd + j * 4096);
#pragma unroll
    for (int j = 0; j < 4; ++j) load_lds16(vgs + j * 131072, vd + j * 4096);
  };

#pragma unroll 1
  for (int ph = 0; ph < 2; ++ph) {
    const int qt = ph ? (15 - pi) : pi;
    const int q0 = qt * 128 + wid * 32;  // this wave's 32-q strip
    const int qv = q0 + c;

    bf16x8 qf[8];
    const short* qbase = qh + ((size_t)(b * 16 + h) * 2048 + qv) * 128;
#pragma unroll
    for (int ki = 0; ki < 8; ++ki) qf[ki] = *(const bf16x8*)(qbase + ki * 16 + hi * 8);

    f32x16 OT[4];
#pragma unroll
    for (int d = 0; d < 4; ++d) OT[d] = zero16();
    float lsum = 0.f;

    const int n = 2 * qt + 2;  // 64-kv steps (n >= 2 always)
    if (ph) __syncthreads();  // all waves done reading bufs from ph=0 before re-staging
    // drain qf loads so the counted vmcnt in the loop is exact (compute is LDS/reg-only)
    asm volatile("s_waitcnt vmcnt(0)" ::: "memory");
    STAGE(0, 0);
    STAGE(1, 1);
    int p = 0;
#pragma unroll 1
    for (int st = 0; st < n; ++st) {
      const int s0 = st * 64;
      // wait for THIS step's tile (8 own loads); keep next tile's 8 in flight
      if (st + 1 < n)
        asm volatile("s_waitcnt vmcnt(8)" ::: "memory");
      else
        asm volatile("s_waitcnt vmcnt(0)" ::: "memory");
      barrier_raw();
      if (st + 2 < n) STAGE(p == 0 ? 2 : p - 1, st + 2);

      if (s0 <= q0 + 31) {  // wave-uniform: skip fully-masked diagonal work
        const char* Ksb = (const char*)Ks[p];
        const char* Vtb = (const char*)Vts[p];

        // S[kv][q] = K Q^T   (two 32-kv blocks)
        f32x16 S0 = zero16(), S1 = zero16();
        __builtin_amdgcn_s_setprio(1);
#pragma unroll
        for (int ki = 0; ki < 8; ++ki) {
          int a0 = (c * 256 + ki * 32 + hi * 16) ^ ((c & 7) << 4);
          bf16x8 k0 = *(const bf16x8*)(Ksb + a0);
          S0 = mfma32(k0, qf[ki], S0);
          bf16x8 k1 = *(const bf16x8*)(Ksb + (a0 + 8192));
          S1 = mfma32(k1, qf[ki], S1);
        }
        __builtin_amdgcn_s_setprio(0);

        // causal mask (only diagonal steps)
        if (s0 + 63 > q0) {
#pragma unroll
          for (int r = 0; r < 16; ++r) {
            int kv0 = s0 + (r & 3) + 8 * (r >> 2) + hi * 4;
            S0[r] = (kv0 > qv) ? -1e30f : S0[r];
            S1[r] = (kv0 + 32 > qv) ? -1e30f : S1[r];
          }
        }

        // P = exp2(S)  (static max = 0; masked entries underflow to 0), 4-acc row-sum
        float ps0 = 0.f, ps1 = 0.f, ps2 = 0.f, ps3 = 0.f;
#pragma unroll
        for (int r = 0; r < 16; r += 4) {
          S0[r] = exp2f(S0[r]);          ps0 += S0[r];
          S0[r + 1] = exp2f(S0[r + 1]);  ps1 += S0[r + 1];
          S0[r + 2] = exp2f(S0[r + 2]);  ps2 += S0[r + 2];
          S0[r + 3] = exp2f(S0[r + 3]);  ps3 += S0[r + 3];
        }
#pragma unroll
        for (int r = 0; r < 16; r += 4) {
          S1[r] = exp2f(S1[r]);          ps0 += S1[r];
          S1[r + 1] = exp2f(S1[r + 1]);  ps1 += S1[r + 1];
          S1[r + 2] = exp2f(S1[r + 2]);  ps2 += S1[r + 2];
          S1[r + 3] = exp2f(S1[r + 3]);  ps3 += S1[r + 3];
        }
        float psum = (ps0 + ps1) + (ps2 + ps3);
        psum += __shfl_xor(psum, 32);
        lsum += psum;

        // pack P to bf16 + cross-half redistribution (proven select table)
        unsigned D[16], sD[16];
#pragma unroll
        for (int i = 0; i < 8; ++i) D[i] = pack2(S0[2 * i], S0[2 * i + 1]);
#pragma unroll
        for (int i = 0; i < 8; ++i) D[8 + i] = pack2(S1[2 * i], S1[2 * i + 1]);
#pragma unroll
        for (int i = 0; i < 16; ++i) sD[i] = (unsigned)__shfl_xor((int)D[i], 32);
        bf16x8 pf[4];
#pragma unroll
        for (int ks = 0; ks < 4; ++ks) {
          int bi = ks * 4;
          u32x4 w;
          w[0] = hi ? sD[bi + 2] : D[bi + 0];
          w[1] = hi ? sD[bi + 3] : D[bi + 1];
          w[2] = hi ? D[bi + 2] : sD[bi + 0];
          w[3] = hi ? D[bi + 3] : sD[bi + 1];
          pf[ks] = __builtin_bit_cast(bf16x8, w);
        }

        // O^T += V^T P
        __builtin_amdgcn_s_setprio(1);
#pragma unroll
        for (int dblk = 0; dblk < 4; ++dblk) {
          int row = dblk * 32 + c;
          int sw = (row & 7) << 4;
#pragma unroll
          for (int ks = 0; ks < 4; ++ks) {
            int a_v = (row * 128 + ks * 32 + hi * 16) ^ sw;
            bf16x8 vf = *(const bf16x8*)(Vtb + a_v);
            OT[dblk] = mfma32(vf, pf[ks], OT[dblk]);
          }
        }
        __builtin_amdgcn_s_setprio(0);
      }

      p = (p == 2) ? 0 : p + 1;
    }

    // epilogue: O^T / lsum -> ao[b][q][h][d], paired-d dword stores
    float inv = 1.f / lsum;
    short* aob = ao + ((size_t)(b * 2048 + qv) * 2048 + h * 128);
#pragma unroll
    for (int dblk = 0; dblk < 4; ++dblk) {
#pragma unroll
      for (int rp = 0; rp < 8; ++rp) {
        int r = rp * 2;
        int dd = dblk * 32 + (r & 3) + 8 * (r >> 2) + hi * 4;
        unsigned w = pack2(OT[dblk][r] * inv, OT[dblk][r + 1] * inv);
        *(unsigned*)(aob + dd) = w;
      }
    }
  }
}

// ---------- launch ----------
extern "C" void kernel_launch(void* const* d_in, const int* in_sizes, int n_in,
                              void* d_out, int out_size, void* d_ws, size_t ws_size,
                              hipStream_t stream) {
  const float* x = (const float*)d_in[0];
  const float* cosb = (const float*)d_in[1];
  const float* sinb = (const float*)d_in[2];
  const float* Wq = (const float*)d_in[3];
  const float* Wk = (const float*)d_in[4];
  const float* Wv = (const float*)d_in[5];
  const float* Wo = (const float*)d_in[6];

  char* ws = (char*)d_ws;
  short* xb = (short*)(ws);                    // 16.78 MB  (aliased as ao later)
  short* wcat = (short*)(ws + 16777216);       // 9.44 MB
  short* wob = (short*)(ws + 26214400);        // 8.39 MB
  short* qkv = (short*)(ws + 34603008);        // 18.87 MB
  short* qh = (short*)(ws + 53477376);         // 16.78 MB
  short* kh = (short*)(ws + 70254592);         // 1.05 MB
  short* vt = (short*)(ws + 71303168);         // 1.05 MB
  short* ao = xb;                              // xb dead after gemm1

  cvt_all_kernel<<<8448, 256, 0, stream>>>(x, Wq, Wk, Wv, Wo, xb, wcat, wob);

  gemm_nt<1><<<576, 256, 0, stream>>>(xb, wcat, qkv, 4096, 2304, 2048);
  rope_kernel<<<4096, 256, 0, stream>>>(qkv, cosb, sinb, qh, kh);
  vtrans_kernel<<<dim3(32, 4, 2), 256, 0, stream>>>(qkv, vt);
  attn_kernel<<<dim3(8, 16, 2), 256, 0, stream>>>(qh, kh, vt, ao);
  gemm_nt<0><<<512, 256, 0, stream>>>(ao, wob, d_out, 4096, 2048, 2048);
}

// Round 3
// 189.754 us; speedup vs baseline: 1.1653x; 1.0939x over previous
//
#include <hip/hip_runtime.h>
#include <hip/hip_bf16.h>

// ---------- types ----------
typedef __attribute__((ext_vector_type(8))) short bf16x8;
typedef __attribute__((ext_vector_type(4))) float f32x4;
typedef __attribute__((ext_vector_type(16))) float f32x16;
typedef __attribute__((ext_vector_type(4))) unsigned u32x4;

#define DEVINL static __device__ __forceinline__
#define GLOBAL_AS __attribute__((address_space(1)))
#define LDS_AS __attribute__((address_space(3)))

DEVINL short f2b(float f) {
  __hip_bfloat16 h = __float2bfloat16(f);
  return __builtin_bit_cast(short, h);
}
DEVINL float b2f(short s) {
  return __bfloat162float(__builtin_bit_cast(__hip_bfloat16, s));
}
// packed f32->bf16 (RNE) : low = a, high = b. One VALU inst (m214-proven).
DEVINL unsigned pack2(float a, float b) {
  unsigned r;
  asm("v_cvt_pk_bf16_f32 %0, %1, %2" : "=v"(r) : "v"(a), "v"(b));
  return r;
}
// dst.hi(lanes 32-63) <-> src.lo(lanes 0-31) exchange, pure VALU (no LDS latency)
DEVINL void swap32(unsigned& x, unsigned& y) {
  asm("v_permlane32_swap_b32 %0, %1" : "+v"(x), "+v"(y));
}
DEVINL float xhalfsum(float v) {  // v + (v from lane^32), via one permlane swap
  float t = v;
  asm("v_permlane32_swap_b32 %0, %1" : "+v"(v), "+v"(t));
  return v + t;
}
DEVINL void load_lds16(const void* g, void* l) {
  __builtin_amdgcn_global_load_lds((const GLOBAL_AS void*)g, (LDS_AS void*)l, 16, 0, 0);
}
DEVINL void barrier_raw() {
  __builtin_amdgcn_sched_barrier(0);
  __builtin_amdgcn_s_barrier();
  __builtin_amdgcn_sched_barrier(0);
}
DEVINL f32x16 mfma32(bf16x8 a, bf16x8 b, f32x16 c) {
  return __builtin_amdgcn_mfma_f32_32x32x16_bf16(a, b, c, 0, 0, 0);
}
DEVINL f32x16 zero16() {
  f32x16 z;
#pragma unroll
  for (int i = 0; i < 16; ++i) z[i] = 0.f;
  return z;
}

// ---------- fused fp32 -> bf16 conversion (x, Wq, Wk, Wv, Wo in one launch) ----------
__global__ __launch_bounds__(256) void cvt_all_kernel(const float* __restrict__ x,
                                                      const float* __restrict__ wq,
                                                      const float* __restrict__ wk,
                                                      const float* __restrict__ wv,
                                                      const float* __restrict__ wo,
                                                      short* __restrict__ xb,
                                                      short* __restrict__ wcat,
                                                      short* __restrict__ wob) {
  int i = blockIdx.x * blockDim.x + threadIdx.x;
  if (i >= 2162688) return;
  const float* src;
  short* dst;
  if (i < 1048576) {
    src = x + (size_t)i * 8;
    dst = xb + (size_t)i * 8;
  } else if (i < 1572864) {
    int j = i - 1048576;
    src = wq + (size_t)j * 8;
    dst = wcat + (size_t)j * 8;
  } else if (i < 1605632) {
    int j = i - 1572864;
    src = wk + (size_t)j * 8;
    dst = wcat + 4194304 + (size_t)j * 8;
  } else if (i < 1638400) {
    int j = i - 1605632;
    src = wv + (size_t)j * 8;
    dst = wcat + 4456448 + (size_t)j * 8;
  } else {
    int j = i - 1638400;
    src = wo + (size_t)j * 8;
    dst = wob + (size_t)j * 8;
  }
  const float4* p = reinterpret_cast<const float4*>(src);
  float4 a = p[0], b = p[1];
  bf16x8 v;
  v[0] = f2b(a.x); v[1] = f2b(a.y); v[2] = f2b(a.z); v[3] = f2b(a.w);
  v[4] = f2b(b.x); v[5] = f2b(b.y); v[6] = f2b(b.z); v[7] = f2b(b.w);
  *reinterpret_cast<bf16x8*>(dst) = v;
}

// ---------- NT GEMM: C[m][n] = sum_k A[m][k]*B[n][k], A [M][K], B [N][K] bf16 ----------
template <int BF16OUT>
__global__ __launch_bounds__(256) void gemm_nt(const short* __restrict__ A,
                                               const short* __restrict__ B,
                                               void* __restrict__ Cv, int M, int N, int K) {
  __shared__ short As[128 * 64];
  __shared__ short Bs[128 * 64];
  const int tid = threadIdx.x;
  const int lane = tid & 63;
  const int wid = tid >> 6;
  const int lr = lane & 15, lg = lane >> 4;
  const int nwg = gridDim.x, cpx = nwg >> 3;
  const int lid = blockIdx.x;
  const int swz = (lid & 7) * cpx + (lid >> 3);
  const int nbn = N >> 7;
  const int bn = swz % nbn, bm = swz / nbn;
  const int wr = wid >> 1, wc = wid & 1;

  f32x4 acc[4][4];
#pragma unroll
  for (int i = 0; i < 4; ++i)
#pragma unroll
    for (int j = 0; j < 4; ++j) acc[i][j] = f32x4{0.f, 0.f, 0.f, 0.f};

  const short* Ag[4];
  const short* Bg[4];
#pragma unroll
  for (int j = 0; j < 4; ++j) {
    int o = j * 4096 + tid * 16;
    int row = o >> 7;
    int src = o ^ ((row & 7) << 4);
    int col = (src & 127) >> 1;
    Ag[j] = A + (size_t)(bm * 128 + row) * K + col;
    Bg[j] = B + (size_t)(bn * 128 + row) * K + col;
  }
  char* Asb = (char*)As;
  char* Bsb = (char*)Bs;
  const int lds_w = wid * 1024;

  for (int kt = 0; kt < K; kt += 64) {
    __syncthreads();
#pragma unroll
    for (int j = 0; j < 4; ++j) load_lds16(Ag[j] + kt, Asb + j * 4096 + lds_w);
#pragma unroll
    for (int j = 0; j < 4; ++j) load_lds16(Bg[j] + kt, Bsb + j * 4096 + lds_w);
    __syncthreads();

#pragma unroll
    for (int kc = 0; kc < 2; ++kc) {
      bf16x8 af[4], bfr[4];
#pragma unroll
      for (int mf = 0; mf < 4; ++mf) {
        int row = wr * 64 + mf * 16 + lr;
        int a_ = (row * 128 + kc * 64 + lg * 16) ^ ((row & 7) << 4);
        af[mf] = *(const bf16x8*)(Asb + a_);
      }
#pragma unroll
      for (int nf = 0; nf < 4; ++nf) {
        int row = wc * 64 + nf * 16 + lr;
        int a_ = (row * 128 + kc * 64 + lg * 16) ^ ((row & 7) << 4);
        bfr[nf] = *(const bf16x8*)(Bsb + a_);
      }
#pragma unroll
      for (int mf = 0; mf < 4; ++mf)
#pragma unroll
        for (int nf = 0; nf < 4; ++nf)
          acc[mf][nf] =
              __builtin_amdgcn_mfma_f32_16x16x32_bf16(af[mf], bfr[nf], acc[mf][nf], 0, 0, 0);
    }
  }

#pragma unroll
  for (int mf = 0; mf < 4; ++mf)
#pragma unroll
    for (int nf = 0; nf < 4; ++nf)
#pragma unroll
      for (int j = 0; j < 4; ++j) {
        int row = bm * 128 + wr * 64 + mf * 16 + lg * 4 + j;
        int col = bn * 128 + wc * 64 + nf * 16 + lr;
        if constexpr (BF16OUT)
          ((short*)Cv)[(size_t)row * N + col] = f2b(acc[mf][nf][j]);
        else
          ((float*)Cv)[(size_t)row * N + col] = acc[mf][nf][j];
      }
}

// ---------- RoPE: qkv [B*T][2304] -> qh [B][H][T][128] (q pre-scaled), kh [B][T][128] ----------
#define QSC 0.031879358f
__global__ __launch_bounds__(256) void rope_kernel(const short* __restrict__ qkv,
                                                   const float* __restrict__ cosb,
                                                   const float* __restrict__ sinb,
                                                   short* __restrict__ qh,
                                                   short* __restrict__ kh) {
  const int bt = blockIdx.x;
  const int b = bt >> 11, t = bt & 2047;
  const int tid = threadIdx.x;
  {
    int h = tid >> 4, d0 = (tid & 15) * 8;
    const short* base = qkv + (size_t)bt * 2304 + h * 128;
    bf16x8 qa = *(const bf16x8*)(base + d0);
    int dp = d0 < 64 ? d0 + 64 : d0 - 64;
    bf16x8 qp = *(const bf16x8*)(base + dp);
    const float* cp = cosb + (size_t)bt * 128 + d0;
    const float* sp = sinb + (size_t)bt * 128 + d0;
    float sgn = d0 < 64 ? -1.f : 1.f;
    bf16x8 r;
#pragma unroll
    for (int e = 0; e < 8; ++e)
      r[e] = f2b((b2f(qa[e]) * cp[e] + sgn * b2f(qp[e]) * sp[e]) * QSC);
    *(bf16x8*)(qh + (((size_t)(b * 16 + h) * 2048 + t) * 128 + d0)) = r;
  }
  if (tid < 16) {
    int d0 = tid * 8;
    const short* base = qkv + (size_t)bt * 2304 + 2048;
    bf16x8 ka = *(const bf16x8*)(base + d0);
    int dp = d0 < 64 ? d0 + 64 : d0 - 64;
    bf16x8 kp = *(const bf16x8*)(base + dp);
    const float* cp = cosb + (size_t)bt * 128 + d0;
    const float* sp = sinb + (size_t)bt * 128 + d0;
    float sgn = d0 < 64 ? -1.f : 1.f;
    bf16x8 r;
#pragma unroll
    for (int e = 0; e < 8; ++e)
      r[e] = f2b(b2f(ka[e]) * cp[e] + sgn * b2f(kp[e]) * sp[e]);
    *(bf16x8*)(kh + ((size_t)bt * 128 + d0)) = r;
  }
}

// ---------- V transpose: qkv v-cols -> vt [B][128][T] ----------
__global__ __launch_bounds__(256) void vtrans_kernel(const short* __restrict__ qkv,
                                                     short* __restrict__ vt) {
  __shared__ short tile[64][33];
  const int tid = threadIdx.x;
  const int t0 = blockIdx.x * 64, d0 = blockIdx.y * 32, b = blockIdx.z;
  {
    int dl = tid & 31, tl0 = tid >> 5;
#pragma unroll
    for (int r = 0; r < 8; ++r) {
      int tl = tl0 + r * 8;
      tile[tl][dl] = qkv[(size_t)(b * 2048 + t0 + tl) * 2304 + 2176 + d0 + dl];
    }
  }
  __syncthreads();
  {
    int dl = tid >> 3, s0 = (tid & 7) * 8;
    bf16x8 v;
#pragma unroll
    for (int e = 0; e < 8; ++e) v[e] = tile[s0 + e][dl];
    *(bf16x8*)(vt + (size_t)(b * 128 + d0 + dl) * 2048 + t0 + s0) = v;
  }
}

// ---------- causal MQA flash attention v12: software-pipelined, all-VALU softmax ----------
// grid (8, H, B), 256 threads = 4 waves x 32 q-rows, 128-q supertiles paired (pi, 15-pi),
// 36 balanced 64-kv steps/block, K/V TRIPLE-buffered mod-3 (96 KiB, 1 blk/CU).
// Serial-chain fix (R1/R2 showed occupancy & staging are NOT the bottleneck; the
// ~7.5k-cyc/step wall is the single-wave dependency chain):
//  (a) QK(t+1) is computed DURING softmax(t): per body
//      vmcnt(0) -> barrier -> STAGE(t+2) -> QK(t+1)->NXT || softmax(CUR,t) -> PV(t).
//      MFMA+ds_read chain of tile t+1 overlaps the VALU softmax of tile t.
//  (b) softmax is now ALL-VALU: the 16 shfl_xor (ds_bpermute, ~120cy lgkm each) of the
//      P-exchange are replaced by 8 v_permlane32_swap_b32 (the proven select table
//      w0/w2 = swap(D[bi],D[bi+2]), w1/w3 = swap(D[bi+1],D[bi+3])); the row-sum
//      shfl_xor(.,32) becomes one swap+add. Zero LDS ops in softmax.
//  (c) pack via v_cvt_pk_bf16_f32 (1 inst / 2 values).
// Static-max softmax as before (Q pre-scaled by 1/sqrt(T)*log2e, P = exp2(S)).
__global__ __launch_bounds__(256) void attn_kernel(const short* __restrict__ qh,
                                                   const short* __restrict__ kh,
                                                   const short* __restrict__ vt,
                                                   short* __restrict__ ao) {
  __shared__ short Ks[3][64 * 128];
  __shared__ short Vts[3][128 * 64];
  const int tid = threadIdx.x, lane = tid & 63, wid = tid >> 6;
  const int c = lane & 31, hi = lane >> 5;
  const int pi = blockIdx.x;  // 0..7
  const int h = blockIdx.y, b = blockIdx.z;

  // staging source (pre-swizzled global addresses; LDS dest stays linear)
  const int o = tid * 16;
  const int ksrc = o ^ (((o >> 8) & 7) << 4);  // K tile: 256-B rows
  const int vsrc = o ^ (((o >> 7) & 7) << 4);  // Vt tile: 128-B rows
  const char* kg = (const char*)kh + (size_t)b * 524288 + ksrc;
  const char* vg = (const char*)vt + (size_t)b * 524288 + ((o >> 7) * 4096 + (vsrc & 127));
  const int ldsw = wid * 1024;

  auto STAGE = [&](int bufp, int st) {
    const int s0 = st * 64;
    char* kd = (char*)Ks[bufp] + ldsw;
    char* vd = (char*)Vts[bufp] + ldsw;
    const char* kgs = kg + s0 * 256;
    const char* vgs = vg + s0 * 2;
#pragma unroll
    for (int j = 0; j < 4; ++j) load_lds16(kgs + j * 4096, kd + j * 4096);
#pragma unroll
    for (int j = 0; j < 4; ++j) load_lds16(vgs + j * 131072, vd + j * 4096);
  };

#pragma unroll 1
  for (int ph = 0; ph < 2; ++ph) {
    const int qt = ph ? (15 - pi) : pi;
    const int q0 = qt * 128 + wid * 32;  // this wave's 32-q strip
    const int qv = q0 + c;

    bf16x8 qf[8];
    const short* qbase = qh + ((size_t)(b * 16 + h) * 2048 + qv) * 128;
#pragma unroll
    for (int ki = 0; ki < 8; ++ki) qf[ki] = *(const bf16x8*)(qbase + ki * 16 + hi * 8);

    f32x16 OT[4];
#pragma unroll
    for (int d = 0; d < 4; ++d) OT[d] = zero16();
    float lsum = 0.f;
    const int n = 2 * qt + 2;  // 64-kv steps; ALWAYS EVEN

    // QK^T of tile (t) from K-buf -> two 32-kv S blocks
    auto QK = [&](const char* Kn, f32x16& N0, f32x16& N1) {
      N0 = zero16();
      N1 = zero16();
#pragma unroll
      for (int ki = 0; ki < 8; ++ki) {
        int a0 = (c * 256 + ki * 32 + hi * 16) ^ ((c & 7) << 4);
        bf16x8 k0 = *(const bf16x8*)(Kn + a0);
        N0 = mfma32(k0, qf[ki], N0);
        bf16x8 k1 = *(const bf16x8*)(Kn + (a0 + 8192));
        N1 = mfma32(k1, qf[ki], N1);
      }
    };

    // softmax(tile t) on C0,C1 (all-VALU) + PV from Vts[t%3]
    auto SMPV = [&](int t, f32x16& C0, f32x16& C1) {
      const int s0 = t * 64;
      if (s0 + 63 > q0) {
#pragma unroll
        for (int r = 0; r < 16; ++r) {
          int kv0 = s0 + (r & 3) + 8 * (r >> 2) + hi * 4;
          C0[r] = (kv0 > qv) ? -1e30f : C0[r];
          C1[r] = (kv0 + 32 > qv) ? -1e30f : C1[r];
        }
      }
      float ps0 = 0.f, ps1 = 0.f, ps2 = 0.f, ps3 = 0.f;
#pragma unroll
      for (int r = 0; r < 16; r += 4) {
        C0[r] = exp2f(C0[r]);          ps0 += C0[r];
        C0[r + 1] = exp2f(C0[r + 1]);  ps1 += C0[r + 1];
        C0[r + 2] = exp2f(C0[r + 2]);  ps2 += C0[r + 2];
        C0[r + 3] = exp2f(C0[r + 3]);  ps3 += C0[r + 3];
      }
#pragma unroll
      for (int r = 0; r < 16; r += 4) {
        C1[r] = exp2f(C1[r]);          ps0 += C1[r];
        C1[r + 1] = exp2f(C1[r + 1]);  ps1 += C1[r + 1];
        C1[r + 2] = exp2f(C1[r + 2]);  ps2 += C1[r + 2];
        C1[r + 3] = exp2f(C1[r + 3]);  ps3 += C1[r + 3];
      }
      lsum += xhalfsum((ps0 + ps1) + (ps2 + ps3));

      // pack P to bf16 (cvt_pk) + cross-half redistribution via permlane32_swap:
      // (w0,w2) = swap(D[bi+0], D[bi+2]); (w1,w3) = swap(D[bi+1], D[bi+3]).
      unsigned D[16];
#pragma unroll
      for (int i = 0; i < 8; ++i) D[i] = pack2(C0[2 * i], C0[2 * i + 1]);
#pragma unroll
      for (int i = 0; i < 8; ++i) D[8 + i] = pack2(C1[2 * i], C1[2 * i + 1]);
      bf16x8 pf[4];
#pragma unroll
      for (int ks = 0; ks < 4; ++ks) {
        int bi = ks * 4;
        unsigned a0 = D[bi + 0], a1 = D[bi + 1], a2 = D[bi + 2], a3 = D[bi + 3];
        swap32(a0, a2);
        swap32(a1, a3);
        u32x4 w;
        w[0] = a0; w[1] = a1; w[2] = a2; w[3] = a3;
        pf[ks] = __builtin_bit_cast(bf16x8, w);
      }

      // O^T += V^T P
      const char* Vtb = (const char*)Vts[t % 3];
#pragma unroll
      for (int dblk = 0; dblk < 4; ++dblk) {
        int row = dblk * 32 + c;
        int sw = (row & 7) << 4;
#pragma unroll
        for (int ks = 0; ks < 4; ++ks) {
          int a_v = (row * 128 + ks * 32 + hi * 16) ^ sw;
          bf16x8 vf = *(const bf16x8*)(Vtb + a_v);
          OT[dblk] = mfma32(vf, pf[ks], OT[dblk]);
        }
      }
    };

    // pipelined body: wait -> barrier -> stage(t+2) -> QK(t+1)->NXT || softmax+PV(t) on CUR
    auto BODYF = [&](int t, f32x16& C0, f32x16& C1, f32x16& N0, f32x16& N1, bool dostage) {
      asm volatile("s_waitcnt vmcnt(0)" ::: "memory");
      barrier_raw();
      if (dostage) STAGE((t + 2) % 3, t + 2);
      QK((const char*)Ks[(t + 1) % 3], N0, N1);
      SMPV(t, C0, C1);
    };

    // ---- prologue ----
    if (ph) __syncthreads();  // all waves done with LDS from ph=0 before re-staging
    asm volatile("s_waitcnt vmcnt(0)" ::: "memory");  // drain qf loads (clean vm counting)
    STAGE(0, 0);
    STAGE(1, 1);
    asm volatile("s_waitcnt vmcnt(8)" ::: "memory");  // tile 0 landed; tile 1 in flight
    barrier_raw();
    f32x16 Sa0, Sa1, Sb0, Sb1;
    QK((const char*)Ks[0], Sa0, Sa1);

    // ---- main loop: pairs keep CUR in Sa at loop exit (n is even) ----
#pragma unroll 1
    for (int t = 0; t + 2 < n; t += 2) {
      BODYF(t, Sa0, Sa1, Sb0, Sb1, true);
      BODYF(t + 1, Sb0, Sb1, Sa0, Sa1, true);
    }
    BODYF(n - 2, Sa0, Sa1, Sb0, Sb1, false);  // QK(n-1), no stage
    SMPV(n - 1, Sb0, Sb1);                    // last tile: no wait/barrier needed

    // ---- epilogue: O^T / lsum -> ao[b][q][h][d], paired-d dword stores ----
    float inv = 1.f / lsum;
    short* aob = ao + ((size_t)(b * 2048 + qv) * 2048 + h * 128);
#pragma unroll
    for (int dblk = 0; dblk < 4; ++dblk) {
#pragma unroll
      for (int rp = 0; rp < 8; ++rp) {
        int r = rp * 2;
        int dd = dblk * 32 + (r & 3) + 8 * (r >> 2) + hi * 4;
        unsigned w = pack2(OT[dblk][r] * inv, OT[dblk][r + 1] * inv);
        *(unsigned*)(aob + dd) = w;
      }
    }
  }
}

// ---------- launch ----------
extern "C" void kernel_launch(void* const* d_in, const int* in_sizes, int n_in,
                              void* d_out, int out_size, void* d_ws, size_t ws_size,
                              hipStream_t stream) {
  const float* x = (const float*)d_in[0];
  const float* cosb = (const float*)d_in[1];
  const float* sinb = (const float*)d_in[2];
  const float* Wq = (const float*)d_in[3];
  const float* Wk = (const float*)d_in[4];
  const float* Wv = (const float*)d_in[5];
  const float* Wo = (const float*)d_in[6];

  char* ws = (char*)d_ws;
  short* xb = (short*)(ws);                    // 16.78 MB  (aliased as ao later)
  short* wcat = (short*)(ws + 16777216);       // 9.44 MB
  short* wob = (short*)(ws + 26214400);        // 8.39 MB
  short* qkv = (short*)(ws + 34603008);        // 18.87 MB
  short* qh = (short*)(ws + 53477376);         // 16.78 MB
  short* kh = (short*)(ws + 70254592);         // 1.05 MB
  short* vt = (short*)(ws + 71303168);         // 1.05 MB
  short* ao = xb;                              // xb dead after gemm1

  cvt_all_kernel<<<8448, 256, 0, stream>>>(x, Wq, Wk, Wv, Wo, xb, wcat, wob);

  gemm_nt<1><<<576, 256, 0, stream>>>(xb, wcat, qkv, 4096, 2304, 2048);
  rope_kernel<<<4096, 256, 0, stream>>>(qkv, cosb, sinb, qh, kh);
  vtrans_kernel<<<dim3(32, 4, 2), 256, 0, stream>>>(qkv, vt);
  attn_kernel<<<dim3(8, 16, 2), 256, 0, stream>>>(qh, kh, vt, ao);
  gemm_nt<0><<<512, 256, 0, stream>>>(ao, wob, d_out, 4096, 2048, 2048);
}